// Round 3
// baseline (610.621 us; speedup 1.0000x reference)
//
#include <hip/hip_runtime.h>

// HausdorffDTLoss: exact separable EDT (fg & bg) per image, then
// mean((pred-target)^2 * (pred_dt^2 + target_dt^2)).
// Identity: g[i] = min_j f[j]+(i-j)^2 = i^2 + min_j (h[j] - 2*i*j),
// h[j] = f[j] + j^2; and min_j (h - 2ij) for i=i0+k is reassociated as
// (h - 2j*i0) - 2j*k so the per-thread i-vector lives in immediates, not VGPRs.
// All intermediates are integers < 2^18 -> fp32 exact (R1 verified absmax 0.0).
//
// R3 vs R2 (435us, spilled: VGPR capped 64, WRITE 103MB): -32 VGPR via the
// reassociation; fused Z+Y in one LDS-resident kernel (write volumes once);
// fused X+loss kernel (A/B never round-trip after Y). 5 launches, ~115MB/image.

#define BIGV 49153.0f            // 3*128^2 + 1, matches reference BIG
constexpr int NVOX = 4194304;    // 2 * 128^3 voxels per image
constexpr int P2 = 129;          // zy LDS row stride: 129%32==1 -> 2-way max (free)
constexpr int P1 = 65;           // xloss LDS row stride

__global__ void zero_kernel(float* out, int* flags) {
    out[0] = 0.0f;
    flags[0] = 0; flags[1] = 0; flags[2] = 0; flags[3] = 0;
}

// Fused binarize + Z-pass + Y-pass over the (y,z) slab of one (b,x).
// blockIdx.y: 0 = fg -> A, 1 = bg -> Bv. 512 thr, 66.5 KB LDS -> 2 blocks/CU.
__global__ __launch_bounds__(512, 4) void zy_kernel(const float* __restrict__ img,
                                                    float* __restrict__ A,
                                                    float* __restrict__ Bv,
                                                    int* __restrict__ flag2) {
    __shared__ float lds[P2 * P2];   // 129x129 (row 128 / col 128 = prefetch slack)
    const int bg  = blockIdx.y;
    float* outv   = bg ? Bv : A;
    const int b   = blockIdx.x >> 7;
    const int x   = blockIdx.x & 127;
    const int sb  = (b * 128 + x) * 16384;   // + y*128 + z
    const int tid = threadIdx.x;

    // stage h[z][y] = (site ? BIG : 0) + z^2 ; site(fg buf)=fg, site(bg buf)=~fg
    bool any = false;
#pragma unroll
    for (int k = 0; k < 32; ++k) {
        int l = tid + k * 512;
        float v = img[sb + l];
        bool fg = v > 0.5f;
        any |= fg;
        int z = l & 127, y = l >> 7;
        float site = bg ? (fg ? 0.0f : BIGV) : (fg ? BIGV : 0.0f);
        lds[z * P2 + y] = site + (float)(z * z);
    }
    if (!bg && __ballot(any) != 0ULL && (tid & 63) == 0) atomicOr(flag2 + b, 1);
    __syncthreads();

    const int c   = tid & 127;          // column (y for Z-pass, z for Y-pass)
    const int i0  = (tid >> 7) * 32;    // output index base
    const float i0f = (float)i0;
    float acc[32];

    // ---- Z-pass: for fixed y=c, envelope along z ----
#pragma unroll
    for (int k = 0; k < 32; ++k) acc[k] = 3.0e38f;
    {
        float jm2 = 0.0f;
        float hc = lds[c];
        for (int j = 0; j < 128; ++j) {
            float hn = lds[(j + 1) * P2 + c];          // 1-deep prefetch (slack row)
            float hp = fmaf(jm2, i0f, hc);
#pragma unroll
            for (int k = 0; k < 32; ++k)
                acc[k] = fminf(acc[k], fmaf(jm2, (float)k, hp));
            jm2 -= 2.0f;
            hc = hn;
        }
    }
    __syncthreads();
#pragma unroll
    for (int k = 0; k < 32; ++k) {      // g[z][y] = acc + z^2, layout [z][y]
        float iif = i0f + (float)k;
        lds[(i0 + k) * P2 + c] = fmaf(iif, iif, acc[k]);
    }
    __syncthreads();

    // ---- Y-pass: for fixed z=c, envelope along y (reads row c) ----
#pragma unroll
    for (int k = 0; k < 32; ++k) acc[k] = 3.0e38f;
    {
        float jm2 = 0.0f, jf = 0.0f;
        const float* row = lds + c * P2;
        float gc = row[0];
        for (int j = 0; j < 128; ++j) {
            float gn = row[j + 1];                      // slack col
            float hp = fmaf(jm2, i0f, fmaf(jf, jf, gc)); // h = g + j^2
#pragma unroll
            for (int k = 0; k < 32; ++k)
                acc[k] = fminf(acc[k], fmaf(jm2, (float)k, hp));
            jm2 -= 2.0f; jf += 1.0f;
            gc = gn;
        }
    }
    __syncthreads();
#pragma unroll
    for (int k = 0; k < 32; ++k) {      // out[y][z] = acc + y^2, layout [y][z]
        float iif = i0f + (float)k;
        lds[(i0 + k) * P2 + c] = fmaf(iif, iif, acc[k]);
    }
    __syncthreads();
#pragma unroll
    for (int k = 0; k < 32; ++k) {      // coalesced store
        int l = tid + k * 512;
        outv[sb + l] = lds[(l >> 7) * P2 + (l & 127)];
    }
}

// Fused X-pass (A and B) + loss partial. Tile = 64 consecutive (y,z) columns of
// one sample. 256 thr, 33.5 KB LDS -> 4 blocks/CU. A/B final values never hit HBM.
__global__ __launch_bounds__(256, 4) void xloss_kernel(const float* __restrict__ pred,
                                                       const float* __restrict__ tgt,
                                                       const float* __restrict__ A,
                                                       const float* __restrict__ Bv,
                                                       const int* __restrict__ flag2,
                                                       float* __restrict__ out) {
    __shared__ float lds[P2 * P1];   // 129 rows x 65
    const int b    = blockIdx.x >> 8;
    const int q0   = (blockIdx.x & 255) * 64;
    const int base = b * 2097152 + q0;    // + x*16384 + c
    const int tid  = threadIdx.x;
    const int c    = tid & 63;
    const int i0   = (tid >> 6) * 32;
    const float i0f = (float)i0;

    float accA[32], accB[32];

    // ---- stage + transform A ----
#pragma unroll
    for (int k = 0; k < 32; ++k) {
        int l = tid + k * 256;
        int cc = l & 63, j = l >> 6;
        float v = A[base + j * 16384 + cc];
        lds[j * P1 + cc] = fmaf((float)j, (float)j, v);
    }
    __syncthreads();
#pragma unroll
    for (int k = 0; k < 32; ++k) accA[k] = 3.0e38f;
    {
        float jm2 = 0.0f;
        float hc = lds[c];
        for (int j = 0; j < 128; ++j) {
            float hn = lds[(j + 1) * P1 + c];
            float hp = fmaf(jm2, i0f, hc);
#pragma unroll
            for (int k = 0; k < 32; ++k)
                accA[k] = fminf(accA[k], fmaf(jm2, (float)k, hp));
            jm2 -= 2.0f;
            hc = hn;
        }
    }
#pragma unroll
    for (int k = 0; k < 32; ++k) {
        float iif = i0f + (float)k;
        accA[k] = fmaf(iif, iif, accA[k]);
    }
    __syncthreads();

    // ---- stage + transform B (reuses LDS) ----
#pragma unroll
    for (int k = 0; k < 32; ++k) {
        int l = tid + k * 256;
        int cc = l & 63, j = l >> 6;
        float v = Bv[base + j * 16384 + cc];
        lds[j * P1 + cc] = fmaf((float)j, (float)j, v);
    }
    __syncthreads();
#pragma unroll
    for (int k = 0; k < 32; ++k) accB[k] = 3.0e38f;
    {
        float jm2 = 0.0f;
        float hc = lds[c];
        for (int j = 0; j < 128; ++j) {
            float hn = lds[(j + 1) * P1 + c];
            float hp = fmaf(jm2, i0f, hc);
#pragma unroll
            for (int k = 0; k < 32; ++k)
                accB[k] = fminf(accB[k], fmaf(jm2, (float)k, hp));
            jm2 -= 2.0f;
            hc = hn;
        }
    }
#pragma unroll
    for (int k = 0; k < 32; ++k) {
        float iif = i0f + (float)k;
        accB[k] = fmaf(iif, iif, accB[k]);
    }

    // ---- loss partial: (p-t)^2 * (sqrt(gA)+sqrt(gB))^2 * guard ----
    float s = 0.0f;
#pragma unroll
    for (int k = 0; k < 32; ++k) {
        int v = base + (i0 + k) * 16384 + c;   // coalesced across c per k
        float p = pred[v], tq = tgt[v];
        float fld = sqrtf(accA[k]) + sqrtf(accB[k]);
        float d = p - tq;
        s += d * d * fld * fld;
    }
    if (!flag2[b]) s = 0.0f;
#pragma unroll
    for (int off = 32; off > 0; off >>= 1) s += __shfl_down(s, off);
    __shared__ float red[4];
    if ((tid & 63) == 0) red[tid >> 6] = s;
    __syncthreads();
    if (tid == 0)
        atomicAdd(out, (red[0] + red[1] + red[2] + red[3]) * (1.0f / 4194304.0f));
}

extern "C" void kernel_launch(void* const* d_in, const int* in_sizes, int n_in,
                              void* d_out, int out_size, void* d_ws, size_t ws_size,
                              hipStream_t stream) {
    const float* pred = (const float*)d_in[0];
    const float* tgt  = (const float*)d_in[1];
    float* out = (float*)d_out;
    float* A   = (float*)d_ws;           // 16.8 MB
    float* Bv  = A + NVOX;               // 16.8 MB
    int* flags = (int*)(Bv + NVOX);      // 4 ints: [pred_b0, pred_b1, tgt_b0, tgt_b1]

    zero_kernel<<<1, 1, 0, stream>>>(out, flags);
    for (int im = 0; im < 2; ++im) {
        const float* img = im ? tgt : pred;
        zy_kernel<<<dim3(256, 2), 512, 0, stream>>>(img, A, Bv, flags + 2 * im);
        xloss_kernel<<<dim3(512), 256, 0, stream>>>(pred, tgt, A, Bv, flags + 2 * im, out);
    }
}

// Round 4
// 368.191 us; speedup vs baseline: 1.6584x; 1.6584x over previous
//
#include <hip/hip_runtime.h>

// HausdorffDTLoss: exact separable EDT (fg & bg) per image, then
// mean((pred-target)^2 * (pred_dt^2 + target_dt^2)).
// Identity: g[i] = min_j f[j]+(i-j)^2 = i^2 + min_j (h[j] - 2*i*j),
// h[j] = f[j] + j^2, reassociated as (h - 2j*i0) - 2j*k so the i-vector is
// immediates. All intermediates are integers < 2^18 -> fp32 exact (R1: absmax 0).
//
// R4 vs R3 (610us, spill: VGPR forced to 64 by min-waves=4, WRITE 78MB):
//  - acc[16]/thread, 512-thread blocks, launch_bounds(512,2) -> 256-VGPR
//    budget, spills impossible (R2+R3 both died on the 64-VGPR tier squeeze)
//  - j processed in pairs -> v_min3_f32: 2 ops -> ~1.6 ops per (i,j)
//  - 3 passes: zpass (binarize+Z, LDS transpose), ypass, xloss (X + loss fused)

#define BIGV 49153.0f            // 3*128^2 + 1, matches reference BIG
constexpr int NVOX = 4194304;    // 2 * 128^3 voxels per image
constexpr int P    = 65;         // LDS row stride: (j*65+c)%32=(j+c)%32 -> 2-way (free)
constexpr int ROWS = 130;        // 128 + 2 rows prefetch slack (read, never used)
constexpr int LSZ  = ROWS * P;   // 8450 floats = 33.8 KB

__global__ void zero_kernel(float* out, int* flags) {
    out[0] = 0.0f;
    flags[0] = 0; flags[1] = 0; flags[2] = 0; flags[3] = 0;
}

// Lower envelope along the LDS rows: acc[k] = min_j (h[j] - 2*j*(i0+k)).
// Paired j with 2-row prefetch; inner op is fma,fma,min3.
__device__ __forceinline__ void envelope(const float* lds, int c, float i0f,
                                         float (&acc)[16]) {
#pragma unroll
    for (int k = 0; k < 16; ++k) acc[k] = 3.0e38f;
    float h0 = lds[c];
    float h1 = lds[P + c];
    float jm2 = 0.0f;                       // -2j
    for (int j = 0; j < 128; j += 2) {
        float n0 = lds[(j + 2) * P + c];    // prefetch next pair (slack rows at end)
        float n1 = lds[(j + 3) * P + c];
        float jb  = jm2 - 2.0f;
        float hp0 = fmaf(jm2, i0f, h0);
        float hp1 = fmaf(jb,  i0f, h1);
#pragma unroll
        for (int k = 0; k < 16; ++k)
            acc[k] = fminf(acc[k], fminf(fmaf(jm2, (float)k, hp0),
                                         fmaf(jb,  (float)k, hp1)));
        jm2 -= 4.0f;
        h0 = n0; h1 = n1;
    }
}

// Binarize + EDT along z (contiguous axis). blockIdx.y: 0 = fg->A, 1 = bg->B.
// Tile: 64 y-columns x 128 z for one (b,x,ychunk). Transposed via LDS both ways.
__global__ __launch_bounds__(512, 2) void zpass_kernel(const float* __restrict__ img,
                                                       float* __restrict__ A,
                                                       float* __restrict__ Bv,
                                                       int* __restrict__ flag2) {
    __shared__ float lds[LSZ];
    const int bg  = blockIdx.y;
    float* outv   = bg ? Bv : A;
    const int t   = blockIdx.x;              // 512: b(2) x x(128) x ychunk(2)
    const int b   = t >> 8;
    const int x   = (t >> 1) & 127;
    const int yc  = t & 1;
    const int sb  = (b * 128 + x) * 16384 + yc * 8192;   // + y*128 + z
    const int tid = threadIdx.x;

    bool any = false;
#pragma unroll
    for (int k = 0; k < 16; ++k) {
        int l = tid + k * 512;               // contiguous 32KB tile
        float v = img[sb + l];
        bool m = v > 0.5f;
        any |= m;
        if (bg) m = !m;                      // bg EDT: sites where fg
        int z = l & 127, y = l >> 7;
        lds[z * P + y] = (m ? BIGV : 0.0f) + (float)(z * z);   // h[z][y]
    }
    if (!bg && __ballot(any) != 0ULL && (tid & 63) == 0) atomicOr(flag2 + b, 1);
    __syncthreads();

    const int c  = tid & 63;                 // y column
    const int i0 = (tid >> 6) * 16;          // z output base
    const float i0f = (float)i0;
    float acc[16];
    envelope(lds, c, i0f, acc);

    __syncthreads();
#pragma unroll
    for (int k = 0; k < 16; ++k) {           // g[z][y] = acc + z^2
        float iif = i0f + (float)k;
        lds[(i0 + k) * P + c] = fmaf(iif, iif, acc[k]);
    }
    __syncthreads();
#pragma unroll
    for (int k = 0; k < 16; ++k) {           // transposed read -> coalesced store
        int l = tid + k * 512;
        outv[sb + l] = lds[(l & 127) * P + (l >> 7)];
    }
}

// EDT along y (stride 128). Tile: 64 z-columns x 128 y for one (b,x,zchunk).
__global__ __launch_bounds__(512, 2) void ypass_kernel(float* __restrict__ A,
                                                       float* __restrict__ Bv) {
    __shared__ float lds[LSZ];
    float* buf = blockIdx.y ? Bv : A;
    const int t   = blockIdx.x;              // 512: b(2) x x(128) x zchunk(2)
    const int b   = t >> 8;
    const int x   = (t >> 1) & 127;
    const int zc  = t & 1;
    const int base = (b * 128 + x) * 16384 + zc * 64;   // + y*128 + c
    const int tid = threadIdx.x;

#pragma unroll
    for (int k = 0; k < 16; ++k) {
        int l = tid + k * 512;
        int cc = l & 63, y = l >> 6;         // lanes -> consecutive cc: coalesced
        float v = buf[base + y * 128 + cc];
        lds[y * P + cc] = fmaf((float)y, (float)y, v);   // h = f + y^2
    }
    __syncthreads();

    const int c  = tid & 63;
    const int i0 = (tid >> 6) * 16;
    const float i0f = (float)i0;
    float acc[16];
    envelope(lds, c, i0f, acc);
#pragma unroll
    for (int k = 0; k < 16; ++k) {
        float iif = i0f + (float)k;
        buf[base + (i0 + k) * 128 + c] = fmaf(iif, iif, acc[k]);  // g = acc + y^2
    }
}

// EDT along x (stride 16384) for A and B + fused loss partial.
// Tile: 64 consecutive (y,z) columns of one sample; final DTs never hit HBM.
__global__ __launch_bounds__(512, 2) void xloss_kernel(const float* __restrict__ pred,
                                                       const float* __restrict__ tgt,
                                                       const float* __restrict__ A,
                                                       const float* __restrict__ Bv,
                                                       const int* __restrict__ flag2,
                                                       float* __restrict__ out) {
    __shared__ float lds[LSZ];
    const int t    = blockIdx.x;             // 512: b(2) x qchunk(256)
    const int b    = t >> 8;
    const int q0   = (t & 255) * 64;
    const int base = b * 2097152 + q0;       // + x*16384 + c
    const int tid  = threadIdx.x;
    const int c    = tid & 63;
    const int i0   = (tid >> 6) * 16;
    const float i0f = (float)i0;

    float accA[16], accB[16];
#pragma unroll
    for (int k = 0; k < 16; ++k) {
        int l = tid + k * 512;
        int cc = l & 63, j = l >> 6;
        lds[j * P + cc] = fmaf((float)j, (float)j, A[base + j * 16384 + cc]);
    }
    __syncthreads();
    envelope(lds, c, i0f, accA);
    __syncthreads();
#pragma unroll
    for (int k = 0; k < 16; ++k) {
        int l = tid + k * 512;
        int cc = l & 63, j = l >> 6;
        lds[j * P + cc] = fmaf((float)j, (float)j, Bv[base + j * 16384 + cc]);
    }
    __syncthreads();
    envelope(lds, c, i0f, accB);

    // loss partial: (p-t)^2 * (sqrt(gA)+sqrt(gB))^2 * guard
    float s = 0.0f;
#pragma unroll
    for (int k = 0; k < 16; ++k) {
        float iif = i0f + (float)k;
        float gA = fmaf(iif, iif, accA[k]);
        float gB = fmaf(iif, iif, accB[k]);
        int v = base + (i0 + k) * 16384 + c; // coalesced across c per k
        float d = pred[v] - tgt[v];
        float fld = sqrtf(gA) + sqrtf(gB);
        s += d * d * fld * fld;
    }
    if (!flag2[b]) s = 0.0f;
#pragma unroll
    for (int off = 32; off > 0; off >>= 1) s += __shfl_down(s, off);
    __shared__ float red[8];
    if ((tid & 63) == 0) red[tid >> 6] = s;
    __syncthreads();
    if (tid == 0) {
        float tot = 0.0f;
#pragma unroll
        for (int w = 0; w < 8; ++w) tot += red[w];
        atomicAdd(out, tot * (1.0f / 4194304.0f));
    }
}

extern "C" void kernel_launch(void* const* d_in, const int* in_sizes, int n_in,
                              void* d_out, int out_size, void* d_ws, size_t ws_size,
                              hipStream_t stream) {
    const float* pred = (const float*)d_in[0];
    const float* tgt  = (const float*)d_in[1];
    float* out = (float*)d_out;
    float* A   = (float*)d_ws;           // 16.8 MB
    float* Bv  = A + NVOX;               // 16.8 MB
    int* flags = (int*)(Bv + NVOX);      // 4 ints: [pred_b0, pred_b1, tgt_b0, tgt_b1]

    zero_kernel<<<1, 1, 0, stream>>>(out, flags);
    for (int im = 0; im < 2; ++im) {
        const float* img = im ? tgt : pred;
        zpass_kernel<<<dim3(512, 2), 512, 0, stream>>>(img, A, Bv, flags + 2 * im);
        ypass_kernel<<<dim3(512, 2), 512, 0, stream>>>(A, Bv);
        xloss_kernel<<<dim3(512), 512, 0, stream>>>(pred, tgt, A, Bv, flags + 2 * im, out);
    }
}

// Round 5
// 342.615 us; speedup vs baseline: 1.7822x; 1.0746x over previous
//
#include <hip/hip_runtime.h>

// HausdorffDTLoss: exact separable EDT (fg & bg) per image, then
// mean((pred-target)^2 * (pred_dt^2 + target_dt^2)).
// Envelope identity: g[i] = min_j f[j]+(i-j)^2 = i^2 + min_j (h[j]-2ij),
// h[j]=f[j]+j^2, reassociated so the i-vector is immediates (R4: absmax 0.0).
//
// R5 vs R4 (368us; zpass 75.8us at VALUBusy 60% though its envelope is only
// ~25us of useful VALU):
//  - z-axis input is BINARY -> O(n) fwd/bwd bit-scan replaces the 128-j
//    envelope (exact incl. empty-column BIG=49153 case), fused with the
//    y-envelope in one LDS-resident kernel (A/B written once, never re-read
//    until xloss).
//  - all intermediates are integers <= 65282 -> u16 LDS (33.5KB / 16.9KB
//    blocks -> 2x resident waves) and u16 global A/B (halves xloss traffic).
//  - LDS packs (j,j+1) in one dword: 1 ds_read_b32 per j-pair in envelopes.

constexpr int BIGI = 49153;      // 3*128^2+1, matches reference BIG exactly
constexpr int NVOX = 4194304;    // 2 * 128^3 voxels per image
constexpr int STZ  = 129;        // zy dword stride: (129q+c)%32=(q+c)%32 -> 2-way (free)
constexpr int STX  = 65;         // xloss dword stride: same property

__global__ void zero_kernel(float* out, int* flags) {
    out[0] = 0.0f;
    flags[0] = 0; flags[1] = 0; flags[2] = 0; flags[3] = 0;
}

// Fused binarize + O(n) z-scan + y-envelope for one (b,x) slab, one polarity
// (blockIdx.y: 0 = fg -> A16, 1 = bg -> B16). 1024 thr, ~35.6KB LDS.
__global__ __launch_bounds__(1024) void zy_kernel(const float* __restrict__ img,
                                                  unsigned short* __restrict__ A16,
                                                  unsigned short* __restrict__ B16,
                                                  int* __restrict__ flag2) {
    __shared__ unsigned int hz[65 * STZ];          // packed u16 pairs: (y-pair, z)
    __shared__ unsigned long long bm[256];         // site bitmasks: [y][z-half]
    const int bg  = blockIdx.y;
    const int b   = blockIdx.x >> 7;
    const int x   = blockIdx.x & 127;
    const int sb  = (b * 128 + x) * 16384;         // + y*128 + z
    const int tid = threadIdx.x;

    // ---- stage: coalesced img read -> per-wave ballot -> bitmask ----
    bool anyfg = false;
#pragma unroll
    for (int k = 0; k < 16; ++k) {
        int l = tid + k * 1024;                    // wave covers (y, z-half) chunk
        float v = img[sb + l];
        bool fg = v > 0.5f;
        anyfg |= fg;
        bool site = bg ? fg : !fg;                 // EDT sites: where f==0
        unsigned long long bal = __ballot(site);
        if ((tid & 63) == 0) bm[l >> 6] = bal;     // l>>6 uniform per wave
    }
    if (!bg && __ballot(anyfg) != 0ULL && (tid & 63) == 0) atomicOr(flag2 + b, 1);
    __syncthreads();

    // ---- O(n) z-scan: thread y builds h[y][z] = f_z + y^2 (u16, exact) ----
    unsigned short* hu = (unsigned short*)hz;
    if (tid < 128) {
        const int y = tid;
        const unsigned long long m0 = bm[2 * y], m1 = bm[2 * y + 1];
        const int rb = ((y >> 1) * STZ) * 2 + (y & 1);   // u16 index of (y, z=0)
        int last = -200;                                  // fwd dist <= 327, fits u16
        unsigned long long m = m0;
        for (int z = 0; z < 64; ++z) {
            if (m & 1) last = z;
            hu[rb + 2 * z] = (unsigned short)(z - last);
            m >>= 1;
        }
        m = m1;
        for (int z = 64; z < 128; ++z) {
            if (m & 1) last = z;
            hu[rb + 2 * z] = (unsigned short)(z - last);
            m >>= 1;
        }
        const int yy = y * y;
        int lastb = 400;
        m = m1;                                           // bwd: MSB-first
        for (int z = 127; z >= 64; --z) {
            if (m >> 63) lastb = z;
            m <<= 1;
            int d = min((int)hu[rb + 2 * z], lastb - z);
            int f = (d <= 127) ? d * d : BIGI;            // empty column -> BIG (exact)
            hu[rb + 2 * z] = (unsigned short)(f + yy);    // <= 65282, fits u16
        }
        m = m0;
        for (int z = 63; z >= 0; --z) {
            if (m >> 63) lastb = z;
            m <<= 1;
            int d = min((int)hu[rb + 2 * z], lastb - z);
            int f = (d <= 127) ? d * d : BIGI;
            hu[rb + 2 * z] = (unsigned short)(f + yy);
        }
    }
    __syncthreads();

    // ---- y-envelope: c = z column, 8 groups x 16 outputs ----
    const int c  = tid & 127;
    const int i0 = (tid >> 7) * 16;
    const float i0f = (float)i0;
    float acc[16];
#pragma unroll
    for (int k = 0; k < 16; ++k) acc[k] = 3.0e38f;
    const unsigned int* pz = hz + c;
    unsigned int vc = pz[0];
    float jm2 = 0.0f;                               // -2*(2q)
    for (int q = 0; q < 64; ++q) {
        unsigned int vn = pz[(q + 1) * STZ];        // 1-pair prefetch (row 64 slack)
        float h0 = (float)(vc & 0xffffu);           // y = 2q
        float h1 = (float)(vc >> 16);               // y = 2q+1
        float jb  = jm2 - 2.0f;
        float hp0 = fmaf(jm2, i0f, h0);
        float hp1 = fmaf(jb,  i0f, h1);
#pragma unroll
        for (int k = 0; k < 16; ++k)
            acc[k] = fminf(acc[k], fminf(fmaf(jm2, (float)k, hp0),
                                         fmaf(jb,  (float)k, hp1)));
        jm2 -= 4.0f;
        vc = vn;
    }
    unsigned short* outv = bg ? B16 : A16;
#pragma unroll
    for (int k = 0; k < 16; ++k) {                  // gy = acc + y^2 <= 49153: u16 exact
        float iif = i0f + (float)k;
        outv[sb + (i0 + k) * 128 + c] = (unsigned short)(unsigned int)fmaf(iif, iif, acc[k]);
    }
}

// X-envelope for A and B (u16 in, LDS packed pairs) + fused loss partial.
// Tile: 64 (y,z) columns x 128 x of one sample. 512 thr, 16.9KB LDS.
__global__ __launch_bounds__(512) void xloss_kernel(const float* __restrict__ pred,
                                                    const float* __restrict__ tgt,
                                                    const unsigned short* __restrict__ A16,
                                                    const unsigned short* __restrict__ B16,
                                                    const int* __restrict__ flag2,
                                                    float* __restrict__ out) {
    __shared__ unsigned int hx[65 * STX];
    const int t    = blockIdx.x;              // 512: b(2) x qchunk(256)
    const int b    = t >> 8;
    const int q0   = (t & 255) * 64;
    const int base = b * 2097152 + q0;        // + x*16384 + c
    const int tid  = threadIdx.x;
    const int c    = tid & 63;
    const int i0   = (tid >> 6) * 16;
    const float i0f = (float)i0;
    unsigned short* hu = (unsigned short*)hx;
    float accA[16], accB[16];

    // ---- stage + envelope A ----
#pragma unroll
    for (int k = 0; k < 16; ++k) {
        int l = tid + k * 512;
        int cc = l & 63, j = l >> 6;
        unsigned int v = A16[base + j * 16384 + cc];
        hu[((j >> 1) * STX + cc) * 2 + (j & 1)] = (unsigned short)(v + j * j); // <=65282
    }
    __syncthreads();
    {
#pragma unroll
        for (int k = 0; k < 16; ++k) accA[k] = 3.0e38f;
        const unsigned int* px = hx + c;
        unsigned int vc = px[0];
        float jm2 = 0.0f;
        for (int q = 0; q < 64; ++q) {
            unsigned int vn = px[(q + 1) * STX];
            float h0 = (float)(vc & 0xffffu);
            float h1 = (float)(vc >> 16);
            float jb  = jm2 - 2.0f;
            float hp0 = fmaf(jm2, i0f, h0);
            float hp1 = fmaf(jb,  i0f, h1);
#pragma unroll
            for (int k = 0; k < 16; ++k)
                accA[k] = fminf(accA[k], fminf(fmaf(jm2, (float)k, hp0),
                                               fmaf(jb,  (float)k, hp1)));
            jm2 -= 4.0f;
            vc = vn;
        }
    }
    __syncthreads();

    // ---- stage + envelope B ----
#pragma unroll
    for (int k = 0; k < 16; ++k) {
        int l = tid + k * 512;
        int cc = l & 63, j = l >> 6;
        unsigned int v = B16[base + j * 16384 + cc];
        hu[((j >> 1) * STX + cc) * 2 + (j & 1)] = (unsigned short)(v + j * j);
    }
    __syncthreads();
    {
#pragma unroll
        for (int k = 0; k < 16; ++k) accB[k] = 3.0e38f;
        const unsigned int* px = hx + c;
        unsigned int vc = px[0];
        float jm2 = 0.0f;
        for (int q = 0; q < 64; ++q) {
            unsigned int vn = px[(q + 1) * STX];
            float h0 = (float)(vc & 0xffffu);
            float h1 = (float)(vc >> 16);
            float jb  = jm2 - 2.0f;
            float hp0 = fmaf(jm2, i0f, h0);
            float hp1 = fmaf(jb,  i0f, h1);
#pragma unroll
            for (int k = 0; k < 16; ++k)
                accB[k] = fminf(accB[k], fminf(fmaf(jm2, (float)k, hp0),
                                               fmaf(jb,  (float)k, hp1)));
            jm2 -= 4.0f;
            vc = vn;
        }
    }

    // ---- loss partial: (p-t)^2 * (sqrt(gA)+sqrt(gB))^2 * guard ----
    float s = 0.0f;
#pragma unroll
    for (int k = 0; k < 16; ++k) {
        float iif = i0f + (float)k;
        float gA = fmaf(iif, iif, accA[k]);
        float gB = fmaf(iif, iif, accB[k]);
        int v = base + (i0 + k) * 16384 + c;     // coalesced across c per k
        float d = pred[v] - tgt[v];
        float fld = sqrtf(gA) + sqrtf(gB);
        s += d * d * fld * fld;
    }
    if (!flag2[b]) s = 0.0f;
#pragma unroll
    for (int off = 32; off > 0; off >>= 1) s += __shfl_down(s, off);
    __shared__ float red[8];
    if ((tid & 63) == 0) red[tid >> 6] = s;
    __syncthreads();
    if (tid == 0) {
        float tot = 0.0f;
#pragma unroll
        for (int w = 0; w < 8; ++w) tot += red[w];
        atomicAdd(out, tot * (1.0f / 4194304.0f));
    }
}

extern "C" void kernel_launch(void* const* d_in, const int* in_sizes, int n_in,
                              void* d_out, int out_size, void* d_ws, size_t ws_size,
                              hipStream_t stream) {
    const float* pred = (const float*)d_in[0];
    const float* tgt  = (const float*)d_in[1];
    float* out = (float*)d_out;
    unsigned short* A16 = (unsigned short*)d_ws;   // 8.4 MB
    unsigned short* B16 = A16 + NVOX;              // 8.4 MB
    int* flags = (int*)(B16 + NVOX);               // [pred_b0, pred_b1, tgt_b0, tgt_b1]

    zero_kernel<<<1, 1, 0, stream>>>(out, flags);
    for (int im = 0; im < 2; ++im) {
        const float* img = im ? tgt : pred;
        zy_kernel<<<dim3(256, 2), 1024, 0, stream>>>(img, A16, B16, flags + 2 * im);
        xloss_kernel<<<dim3(512), 512, 0, stream>>>(pred, tgt, A16, B16, flags + 2 * im, out);
    }
}